// Round 1
// 496.446 us; speedup vs baseline: 1.1871x; 1.1871x over previous
//
#include <hip/hip_runtime.h>
#include <hip/hip_bf16.h>
#include <math.h>

#define R 10
#define C 6
#define HID 128
#define HEADS 4
#define NL 3
#define KO 512            // HEADS*HID
#define TOK 1280          // R*HID
#define NCAT 544          // padded GEMM N: 512 xp + 8 logit cols + pad
#define NT 33             // ceil(520/16) N-tiles
#define NUSE 520
#define XPH 528           // s_xph row stride (halves), 1056B rows (8B-aligned)
#define HS 132            // s_h row stride (floats) during encoder/LN phase
#define NFS 136           // s_nfb row stride (bf16 elems), 272B rows -> 2-way-free banks
#define LN_EPS 1e-5f
#define NEG_SLOPE 0.2f
#define MAXE 40
#define MAXDEG 16

typedef __attribute__((ext_vector_type(8))) short short8;
typedef __attribute__((ext_vector_type(4))) float floatx4;
typedef _Float16 half4v __attribute__((ext_vector_type(4)));

__device__ __forceinline__ float gelu_exact(float v) {
    return 0.5f * v * (1.0f + erff(v * 0.70710678118654752440f));
}
__device__ __forceinline__ short f2bf(float v) {
    __hip_bfloat16 b = __float2bfloat16(v);
    return __builtin_bit_cast(short, b);
}

// ---- prep: Wcat[l][n][k] bf16, n-major k-contiguous ----
// n in [0,512): W^T columns; n in [512,516): W@asrc_h folded; [516,520): W@adst_h; rest 0.
__global__ void prep_wcat(const float* __restrict__ Wg,
                          const float* __restrict__ asrc,
                          const float* __restrict__ adst,
                          short* __restrict__ Wcat)
{
    int idx = blockIdx.x * 256 + threadIdx.x;
    const int TOTAL = NL * NCAT * HID;
    if (idx >= TOTAL) return;
    int k = idx & (HID - 1);
    int n = (idx >> 7) % NCAT;
    int l = idx / (NCAT * HID);
    float v = 0.f;
    if (n < KO) {
        v = Wg[((size_t)l * HID + k) * KO + n];
    } else if (n < KO + 8) {
        int h = (n - KO) & 3;
        const float* a = ((n - KO) < 4 ? asrc : adst) + (l * HEADS + h) * HID;
        const float* w = Wg + ((size_t)l * HID + k) * KO + h * HID;
        float s = 0.f;
        for (int f = 0; f < HID; ++f) s = fmaf(w[f], a[f], s);
        v = s;
    }
    Wcat[idx] = f2bf(v);
}

__global__ __launch_bounds__(256, 5) void fused_gnn_mfma(
    const float* __restrict__ x,      // (BT, 60)
    const float* __restrict__ Wenc,   // (R, C, HID)
    const float* __restrict__ benc,   // (R, HID)
    const float* __restrict__ gamma_, // (R, HID)
    const float* __restrict__ beta_,  // (R, HID)
    const short* __restrict__ Wcat,   // (NL, NCAT, HID) bf16
    const float* __restrict__ bg,     // (NL, HID)
    const int* __restrict__ srce, const int* __restrict__ dste,
    float* __restrict__ gf_out, float* __restrict__ rf_out, int E)
{
    // union: encoder-phase fp32 h[2][10][HS] (10560B) | GAT-phase fp16 xp[2][10][XPH] (21120B)
    __shared__ __align__(16) char s_big[2 * R * XPH * 2];   // 21120 B
    __shared__ __align__(16) short s_nfb[2 * R * NFS];      // 5440 B: nf bf16, MFMA-A layout
    __shared__ float s_un[320];         // union: enc {xr[120],mu[20]@128,rs[20]@148} | alpha[2][40][4]
    __shared__ float s_logit[2 * R * 8]; // fp32 GEMM logit cols (al_src[0:4], al_dst[4:8])
    __shared__ int s_src[MAXE], s_dst[MAXE];
    __shared__ int s_eid[R * MAXDEG], s_deg[R];

    float* s_h = reinterpret_cast<float*>(s_big);          // encoder/LN phase only
    _Float16* s_xph = reinterpret_cast<_Float16*>(s_big);  // GAT phase only

    const int t = threadIdx.x;
    const int lane = t & 63;
    const int wave = t >> 6;
    const int tok0 = blockIdx.x * 2;

    // ---- stage edges + x (both tokens contiguous: 120 floats) ----
    if (t < E) { s_src[t] = srce[t]; s_dst[t] = dste[t]; }
    if (t < 120) s_un[t] = x[(size_t)tok0 * 60 + t];
    __syncthreads();
    if (t < R) {
        int d = 0;
        for (int e = 0; e < E; ++e)
            if (s_dst[e] == t && d < MAXDEG) s_eid[t * MAXDEG + (d++)] = e;
        s_deg[t] = d;
    }

    // ---- encoder: h = x @ Wenc + benc, per-quad mapping q=(tk,r,f4) ----
    for (int q = t; q < 640; q += 256) {
        int tk = q >= 320; int qq = q - tk * 320;
        int r = qq >> 5; int f4 = (qq & 31) << 2;
        const float* xr = &s_un[tk * 60 + r * 6];
        float4 acc = *(const float4*)&benc[r * HID + f4];
        #pragma unroll
        for (int c = 0; c < 6; ++c) {
            float xv = xr[c];
            float4 wv = *(const float4*)&Wenc[(r * 6 + c) * HID + f4];
            acc.x = fmaf(xv, wv.x, acc.x);
            acc.y = fmaf(xv, wv.y, acc.y);
            acc.z = fmaf(xv, wv.z, acc.z);
            acc.w = fmaf(xv, wv.w, acc.w);
        }
        *(float4*)&s_h[(tk * R + r) * HS + f4] = acc;
    }
    __syncthreads();

    // ---- LayerNorm stats: one wave per row ----
    for (int rr = wave; rr < 20; rr += 4) {
        const float* row = &s_h[rr * HS];
        float v0 = row[lane], v1 = row[lane + 64];
        float sum = v0 + v1, sq = v0 * v0 + v1 * v1;
        #pragma unroll
        for (int off = 32; off > 0; off >>= 1) {
            sum += __shfl_down(sum, off);
            sq  += __shfl_down(sq,  off);
        }
        if (lane == 0) {
            float mu = sum * (1.0f / HID);
            float var = sq * (1.0f / HID) - mu * mu;
            s_un[128 + rr] = mu;
            s_un[148 + rr] = rsqrtf(var + LN_EPS);
        }
    }
    __syncthreads();

    // ---- normalize + affine + gelu -> nf_reg (residual), s_nfb (bf16 A), rf_out ----
    float4 nf_reg[3];
    {
        int nq = 0;
        for (int q = t; q < 640; q += 256, ++nq) {
            int tk = q >= 320; int qq = q - tk * 320;
            int r = qq >> 5; int f4 = (qq & 31) << 2;
            float4 v = *(const float4*)&s_h[(tk * R + r) * HS + f4];
            float mu = s_un[128 + tk * 10 + r];
            float rs = s_un[148 + tk * 10 + r];
            float4 g = *(const float4*)&gamma_[r * HID + f4];
            float4 b = *(const float4*)&beta_[r * HID + f4];
            float4 o;
            o.x = gelu_exact((v.x - mu) * rs * g.x + b.x);
            o.y = gelu_exact((v.y - mu) * rs * g.y + b.y);
            o.z = gelu_exact((v.z - mu) * rs * g.z + b.z);
            o.w = gelu_exact((v.w - mu) * rs * g.w + b.w);
            nf_reg[nq] = o;
            short4 pk; pk.x = f2bf(o.x); pk.y = f2bf(o.y); pk.z = f2bf(o.z); pk.w = f2bf(o.w);
            *(short4*)&s_nfb[(tk * R + r) * NFS + f4] = pk;
            *(float4*)&rf_out[(size_t)(tok0 + tk) * TOK + qq * 4] = o;
        }
    }
    __syncthreads();

    // ---- 3 GAT layers ----
    const int col = lane & 15;
    const int quad = lane >> 4;
    const int aoff = quad * 8;
    const int crow = (col < R) ? col : 0;  // rows 10..15 of the A tile are don't-care

    for (int l = 0; l < NL; ++l) {
        const short* __restrict__ Wl = Wcat + (size_t)l * NCAT * HID;

        // A fragments: rows m=lane&15 (clamped), k=quad*8+j (+32 per kstep)
        short8 aF[2][4];
        #pragma unroll
        for (int tk = 0; tk < 2; ++tk)
            #pragma unroll
            for (int ks = 0; ks < 4; ++ks)
                aF[tk][ks] = *(const short8*)&s_nfb[(tk * R + crow) * NFS + ks * 32 + aoff];

        // GEMM: N-tiles round-robin over waves; B frags straight from L2 (bf16, coalesced)
        for (int nt = wave; nt < NT; nt += 4) {
            const short* Bp = Wl + (nt * 16 + col) * HID + aoff;
            short8 b0 = *(const short8*)(Bp);
            short8 b1 = *(const short8*)(Bp + 32);
            short8 b2 = *(const short8*)(Bp + 64);
            short8 b3 = *(const short8*)(Bp + 96);
            int n = nt * 16 + col;
            #pragma unroll
            for (int tk = 0; tk < 2; ++tk) {
                floatx4 c = {0.f, 0.f, 0.f, 0.f};
                c = __builtin_amdgcn_mfma_f32_16x16x32_bf16(aF[tk][0], b0, c, 0, 0, 0);
                c = __builtin_amdgcn_mfma_f32_16x16x32_bf16(aF[tk][1], b1, c, 0, 0, 0);
                c = __builtin_amdgcn_mfma_f32_16x16x32_bf16(aF[tk][2], b2, c, 0, 0, 0);
                c = __builtin_amdgcn_mfma_f32_16x16x32_bf16(aF[tk][3], b3, c, 0, 0, 0);
                if (n < KO) {
                    #pragma unroll
                    for (int j = 0; j < 4; ++j) {
                        int m = quad * 4 + j;          // C row = region
                        if (m < R) s_xph[(tk * R + m) * XPH + n] = (_Float16)c[j];
                    }
                } else if (n < NUSE) {
                    #pragma unroll
                    for (int j = 0; j < 4; ++j) {
                        int m = quad * 4 + j;
                        if (m < R) s_logit[(tk * R + m) * 8 + (n - KO)] = c[j];
                    }
                }
            }
        }
        __syncthreads();

        // ---- segment softmax per (token, dst node, head): 80 threads ----
        if (t < 80) {
            int tk = t / 40; int rem = t - tk * 40;
            int r = rem >> 2; int h = rem & 3;
            const float* lg = &s_logit[tk * R * 8];
            float ald = lg[r * 8 + 4 + h];
            int d = s_deg[r];
            float m = -1e30f;
            for (int k = 0; k < d; ++k) {
                int e = s_eid[r * MAXDEG + k];
                float val = lg[s_src[e] * 8 + h] + ald;
                val = (val > 0.f) ? val : NEG_SLOPE * val;
                m = fmaxf(m, val);
            }
            float ssum = 0.f;
            for (int k = 0; k < d; ++k) {
                int e = s_eid[r * MAXDEG + k];
                float val = lg[s_src[e] * 8 + h] + ald;
                val = (val > 0.f) ? val : NEG_SLOPE * val;
                ssum += expf(val - m);
            }
            float inv = 1.0f / ssum;
            for (int k = 0; k < d; ++k) {
                int e = s_eid[r * MAXDEG + k];
                float val = lg[s_src[e] * 8 + h] + ald;
                val = (val > 0.f) ? val : NEG_SLOPE * val;
                s_un[(tk * 40 + e) * 4 + h] = expf(val - m) * inv;
            }
        }
        __syncthreads();

        // ---- aggregate + mean heads + bias + gelu + residual ----
        {
            int nq = 0;
            for (int q = t; q < 640; q += 256, ++nq) {
                int tk = q >= 320; int qq = q - tk * 320;
                int r = qq >> 5; int f4 = (qq & 31) << 2;
                float4 acc = {0.f, 0.f, 0.f, 0.f};
                int d = s_deg[r];
                const _Float16* xb = &s_xph[tk * R * XPH];
                for (int k = 0; k < d; ++k) {
                    int e = s_eid[r * MAXDEG + k];
                    const _Float16* row = xb + s_src[e] * XPH;
                    #pragma unroll
                    for (int h = 0; h < 4; ++h) {
                        float a = s_un[(tk * 40 + e) * 4 + h];
                        half4v xv = *(const half4v*)&row[h * HID + f4];
                        acc.x = fmaf(a, (float)xv.x, acc.x);
                        acc.y = fmaf(a, (float)xv.y, acc.y);
                        acc.z = fmaf(a, (float)xv.z, acc.z);
                        acc.w = fmaf(a, (float)xv.w, acc.w);
                    }
                }
                float4 bb = *(const float4*)&bg[l * HID + f4];
                float4 o;
                o.x = gelu_exact(acc.x * 0.25f + bb.x) + nf_reg[nq].x;
                o.y = gelu_exact(acc.y * 0.25f + bb.y) + nf_reg[nq].y;
                o.z = gelu_exact(acc.z * 0.25f + bb.z) + nf_reg[nq].z;
                o.w = gelu_exact(acc.w * 0.25f + bb.w) + nf_reg[nq].w;
                nf_reg[nq] = o;
                if (l < NL - 1) {
                    short4 pk; pk.x = f2bf(o.x); pk.y = f2bf(o.y); pk.z = f2bf(o.z); pk.w = f2bf(o.w);
                    *(short4*)&s_nfb[(tk * R + r) * NFS + f4] = pk;
                }
            }
        }
        __syncthreads();
    }

    // ---- write graph_features ----
    {
        int nq = 0;
        for (int q = t; q < 640; q += 256, ++nq) {
            int tk = q >= 320; int qq = q - tk * 320;
            *(float4*)&gf_out[(size_t)(tok0 + tk) * TOK + qq * 4] = nf_reg[nq];
        }
    }
}

extern "C" void kernel_launch(void* const* d_in, const int* in_sizes, int n_in,
                              void* d_out, int out_size, void* d_ws, size_t ws_size,
                              hipStream_t stream) {
    const float* x      = (const float*)d_in[0];
    const float* Wenc   = (const float*)d_in[1];
    const float* benc   = (const float*)d_in[2];
    const float* gamma_ = (const float*)d_in[3];
    const float* beta_  = (const float*)d_in[4];
    const float* Wg     = (const float*)d_in[5];
    const float* asrc   = (const float*)d_in[6];
    const float* adst   = (const float*)d_in[7];
    const float* bg     = (const float*)d_in[8];
    const int*   srce   = (const int*)d_in[9];
    const int*   dste   = (const int*)d_in[10];

    const int E  = in_sizes[9];
    const int BT = in_sizes[0] / (R * C);   // 12800

    float* gf = (float*)d_out;
    float* rf = gf + (size_t)BT * TOK;
    short* Wcat = (short*)d_ws;             // NL*NCAT*HID bf16 = 816 KB

    const int prep_total = NL * NCAT * HID;
    prep_wcat<<<(prep_total + 255) / 256, 256, 0, stream>>>(Wg, asrc, adst, Wcat);
    fused_gnn_mfma<<<BT / 2, 256, 0, stream>>>(x, Wenc, benc, gamma_, beta_,
                                               Wcat, bg, srce, dste, gf, rf, E);
}